// Round 4
// baseline (7729.513 us; speedup 1.0000x reference)
//
#include <hip/hip_runtime.h>
#include <math.h>

static __device__ __forceinline__ float sigf(float v) { return 1.0f / (1.0f + expf(-v)); }

static __device__ __forceinline__ void fma4(float4& acc, float s, const float4& wv) {
  acc.x = fmaf(s, wv.x, acc.x);
  acc.y = fmaf(s, wv.y, acc.y);
  acc.z = fmaf(s, wv.z, acc.z);
  acc.w = fmaf(s, wv.w, acc.w);
}

// ---------------------------------------------------------------------------
// GEMM: C[M,N] = act(A[M,K] @ B[N,K]^T + bias[N]);  act: 0=none, 1=relu, 2=tanh
// 128x128 tile, BK=16, 256 threads, 8x8 per thread.
// Requires M%128==0, N%128==0, K%16==0.
// ---------------------------------------------------------------------------
__global__ __launch_bounds__(256) void gemm128(
    const float* __restrict__ A, const float* __restrict__ Bw,
    const float* __restrict__ bias, float* __restrict__ C,
    int M, int N, int K, int act)
{
  __shared__ float As[16][132];
  __shared__ float Bs[16][132];
  const int tid = threadIdx.x;
  const int tm = tid & 15, tn = tid >> 4;
  const int m0 = blockIdx.x * 128, n0 = blockIdx.y * 128;
  float acc[8][8];
#pragma unroll
  for (int i = 0; i < 8; ++i)
#pragma unroll
    for (int j = 0; j < 8; ++j) acc[i][j] = 0.f;

  for (int k0 = 0; k0 < K; k0 += 16) {
#pragma unroll
    for (int u = 0; u < 2; ++u) {
      int s = tid + u * 256;
      int row = s >> 2, kc = (s & 3) << 2;
      float4 a = *(const float4*)(A + (size_t)(m0 + row) * K + k0 + kc);
      As[kc + 0][row] = a.x; As[kc + 1][row] = a.y;
      As[kc + 2][row] = a.z; As[kc + 3][row] = a.w;
      float4 b = *(const float4*)(Bw + (size_t)(n0 + row) * K + k0 + kc);
      Bs[kc + 0][row] = b.x; Bs[kc + 1][row] = b.y;
      Bs[kc + 2][row] = b.z; Bs[kc + 3][row] = b.w;
    }
    __syncthreads();
#pragma unroll
    for (int k = 0; k < 16; ++k) {
      float av[8], bv[8];
      *(float4*)(av)     = *(const float4*)&As[k][tm * 8];
      *(float4*)(av + 4) = *(const float4*)&As[k][tm * 8 + 4];
      *(float4*)(bv)     = *(const float4*)&Bs[k][tn * 8];
      *(float4*)(bv + 4) = *(const float4*)&Bs[k][tn * 8 + 4];
#pragma unroll
      for (int i = 0; i < 8; ++i)
#pragma unroll
        for (int j = 0; j < 8; ++j) acc[i][j] = fmaf(av[i], bv[j], acc[i][j]);
    }
    __syncthreads();
  }
#pragma unroll
  for (int i = 0; i < 8; ++i) {
    int row = m0 + tm * 8 + i;
    float out[8];
#pragma unroll
    for (int j = 0; j < 8; ++j) {
      float v = acc[i][j] + bias[n0 + tn * 8 + j];
      if (act == 1) v = fmaxf(v, 0.f);
      else if (act == 2) v = tanhf(v);
      out[j] = v;
    }
    *(float4*)(C + (size_t)row * N + n0 + tn * 8)     = *(float4*)out;
    *(float4*)(C + (size_t)row * N + n0 + tn * 8 + 4) = *(float4*)(out + 4);
  }
}

// ---------------------------------------------------------------------------
// Same contract, 64x64 tile, BK=16, 256 threads, 4x4 per thread.
// Requires M%64==0, N%64==0, K%16==0.
// ---------------------------------------------------------------------------
__global__ __launch_bounds__(256) void gemm64(
    const float* __restrict__ A, const float* __restrict__ Bw,
    const float* __restrict__ bias, float* __restrict__ C,
    int M, int N, int K, int act)
{
  __shared__ float As[16][68];
  __shared__ float Bs[16][68];
  const int tid = threadIdx.x;
  const int tm = tid & 15, tn = tid >> 4;
  const int m0 = blockIdx.x * 64, n0 = blockIdx.y * 64;
  float acc[4][4];
#pragma unroll
  for (int i = 0; i < 4; ++i)
#pragma unroll
    for (int j = 0; j < 4; ++j) acc[i][j] = 0.f;

  for (int k0 = 0; k0 < K; k0 += 16) {
    {
      int s = tid;
      int row = s >> 2, kc = (s & 3) << 2;
      float4 a = *(const float4*)(A + (size_t)(m0 + row) * K + k0 + kc);
      As[kc + 0][row] = a.x; As[kc + 1][row] = a.y;
      As[kc + 2][row] = a.z; As[kc + 3][row] = a.w;
      float4 b = *(const float4*)(Bw + (size_t)(n0 + row) * K + k0 + kc);
      Bs[kc + 0][row] = b.x; Bs[kc + 1][row] = b.y;
      Bs[kc + 2][row] = b.z; Bs[kc + 3][row] = b.w;
    }
    __syncthreads();
#pragma unroll
    for (int k = 0; k < 16; ++k) {
      float av[4], bv[4];
      *(float4*)(av) = *(const float4*)&As[k][tm * 4];
      *(float4*)(bv) = *(const float4*)&Bs[k][tn * 4];
#pragma unroll
      for (int i = 0; i < 4; ++i)
#pragma unroll
        for (int j = 0; j < 4; ++j) acc[i][j] = fmaf(av[i], bv[j], acc[i][j]);
    }
    __syncthreads();
  }
#pragma unroll
  for (int i = 0; i < 4; ++i) {
    int row = m0 + tm * 4 + i;
    float out[4];
#pragma unroll
    for (int j = 0; j < 4; ++j) {
      float v = acc[i][j] + bias[n0 + tn * 4 + j];
      if (act == 1) v = fmaxf(v, 0.f);
      else if (act == 2) v = tanhf(v);
      out[j] = v;
    }
    *(float4*)(C + (size_t)row * N + n0 + tn * 4) = *(float4*)out;
  }
}

// ---------------------------------------------------------------------------
// Weight prep: wihT[k][r] = wih[r][k], whhT[k][r] = whh[r][k], bsum = bih+bhh
// wih/whh are (1024, 256) row-major. grid 1024 x 256 threads.
// ---------------------------------------------------------------------------
__global__ __launch_bounds__(256) void prep_cell(
    const float* __restrict__ wih, const float* __restrict__ whh,
    const float* __restrict__ bih, const float* __restrict__ bhh,
    float* __restrict__ wihT, float* __restrict__ whhT, float* __restrict__ bsum)
{
  int t = blockIdx.x * 256 + threadIdx.x;   // 0 .. 262143
  int r = t >> 8;                           // 0..1023 (gate row)
  int k = t & 255;                          // 0..255
  wihT[k * 1024 + r] = wih[r * 256 + k];
  whhT[k * 1024 + r] = whh[r * 256 + k];
  if (k == 0) bsum[r] = bih[r] + bhh[r];
}

// ---------------------------------------------------------------------------
// Fused LSTM cell, B=256, H=256.
// MODE 0: gates init from xg (precomputed x@wihT + bih + bhh); only h@whhT added.
// MODE 1: gates init from bias (bih+bhh); only h@whhT added (x == 0).
// MODE 2: gates init from bias; both x@wihT and h@whhT added.
// Block: 256 threads = 8 batch rows x 32 j-groups (4 j each). Grid: (32, 2).
// ---------------------------------------------------------------------------
template <int MODE>
__global__ __launch_bounds__(256) void lstm_cell(
    const float* __restrict__ xg, const float* __restrict__ x,
    const float* __restrict__ wihT, const float* __restrict__ whhT,
    const float* __restrict__ bias,
    const float* __restrict__ h_in, const float* __restrict__ c_in,
    float* __restrict__ h_out, float* __restrict__ c_out,
    float* __restrict__ h_copy)
{
  __shared__ float hs[8][256];
  __shared__ float xs[8][256];
  const int tid = threadIdx.x;
  const int ji = tid & 31, bi = tid >> 5;
  const int bb = blockIdx.x * 8;
  const int jb = blockIdx.y;            // 0..1
  const int f4 = jb * 32 + ji;          // float4 index inside one gate block (0..63)

  for (int s = tid; s < 512; s += 256) {
    int r = s >> 6, cc = (s & 63) << 2;
    *(float4*)&hs[r][cc] = *(const float4*)&h_in[(bb + r) * 256 + cc];
    if (MODE == 2)
      *(float4*)&xs[r][cc] = *(const float4*)&x[(bb + r) * 256 + cc];
  }
  __syncthreads();

  float4 a0, a1, a2, a3;
  if (MODE == 0) {
    const float4* xr = (const float4*)(xg + (size_t)(bb + bi) * 1024);
    a0 = xr[f4]; a1 = xr[64 + f4]; a2 = xr[128 + f4]; a3 = xr[192 + f4];
  } else {
    const float4* br = (const float4*)bias;
    a0 = br[f4]; a1 = br[64 + f4]; a2 = br[128 + f4]; a3 = br[192 + f4];
  }

#pragma unroll 2
  for (int k = 0; k < 256; ++k) {
    const float ha = hs[bi][k];
    const float4* wr = (const float4*)(whhT + (size_t)k * 1024);
    fma4(a0, ha, wr[f4]);
    fma4(a1, ha, wr[64 + f4]);
    fma4(a2, ha, wr[128 + f4]);
    fma4(a3, ha, wr[192 + f4]);
    if (MODE == 2) {
      const float xa = xs[bi][k];
      const float4* vr = (const float4*)(wihT + (size_t)k * 1024);
      fma4(a0, xa, vr[f4]);
      fma4(a1, xa, vr[64 + f4]);
      fma4(a2, xa, vr[128 + f4]);
      fma4(a3, xa, vr[192 + f4]);
    }
  }

  const int b = bb + bi;
  const int j = jb * 128 + ji * 4;
  const float4 cold = *(const float4*)&c_in[b * 256 + j];
  float4 cn, hn;
  cn.x = sigf(a1.x) * cold.x + sigf(a0.x) * tanhf(a2.x);
  cn.y = sigf(a1.y) * cold.y + sigf(a0.y) * tanhf(a2.y);
  cn.z = sigf(a1.z) * cold.z + sigf(a0.z) * tanhf(a2.z);
  cn.w = sigf(a1.w) * cold.w + sigf(a0.w) * tanhf(a2.w);
  hn.x = sigf(a3.x) * tanhf(cn.x);
  hn.y = sigf(a3.y) * tanhf(cn.y);
  hn.z = sigf(a3.z) * tanhf(cn.z);
  hn.w = sigf(a3.w) * tanhf(cn.w);
  *(float4*)&c_out[b * 256 + j] = cn;
  *(float4*)&h_out[b * 256 + j] = hn;
  if (h_copy) *(float4*)&h_copy[b * 256 + j] = hn;
}

// ---------------------------------------------------------------------------

extern "C" void kernel_launch(void* const* d_in, const int* in_sizes, int n_in,
                              void* d_out, int out_size, void* d_ws, size_t ws_size,
                              hipStream_t stream)
{
  const float* x_in  = (const float*)d_in[0];
  const float* w_en1 = (const float*)d_in[1];
  const float* b_en1 = (const float*)d_in[2];
  const float* w_en2 = (const float*)d_in[3];
  const float* b_en2 = (const float*)d_in[4];
  const float* cw[6][4];
  for (int i = 0; i < 6; ++i)
    for (int j = 0; j < 4; ++j) cw[i][j] = (const float*)d_in[5 + i * 4 + j];
  const float* w_de1 = (const float*)d_in[29];
  const float* b_de1 = (const float*)d_in[30];
  const float* w_de2 = (const float*)d_in[31];
  const float* b_de2 = (const float*)d_in[32];
  float* out = (float*)d_out;

  // ---- workspace layout (floats) ----
  float* ws = (float*)d_ws;
  float* wihT   = ws;                       // 6 * 262144
  float* whhT   = wihT + 6 * 262144;        // 6 * 262144
  float* bsum   = whhT + 6 * 262144;        // 6 * 1024
  float* states = bsum + 6 * 1024;          // 24 * 65536 (12 tensors x ping-pong)
  float* H3     = states + 24 * 65536;      // 10 * 65536
  float* R1     = H3 + 10 * 65536;          // 5242880  (z1 -> xg -> y1)
  float* R2     = R1 + 5242880;             // 1310720  (z2)

  // ---- weight prep + state zero-init (must run every call) ----
  for (int i = 0; i < 6; ++i)
    prep_cell<<<1024, 256, 0, stream>>>(cw[i][0], cw[i][1], cw[i][2], cw[i][3],
                                        wihT + i * 262144, whhT + i * 262144,
                                        bsum + i * 1024);
  hipMemsetAsync(states, 0, (size_t)24 * 65536 * sizeof(float), stream);

  // ---- batched feedforward over all 20 encoder steps ----
  float* z1 = R1;
  float* z2 = R2;
  gemm128<<<dim3(5120 / 128, 1024 / 128), 256, 0, stream>>>(
      x_in, w_en1, b_en1, z1, 5120, 1024, 4096, 1);
  gemm64<<<dim3(5120 / 64, 256 / 64), 256, 0, stream>>>(
      z1, w_en2, b_en2, z2, 5120, 256, 1024, 1);
  float* xg = R1;  // z1 dead; reuse
  gemm64<<<dim3(5120 / 64, 1024 / 64), 256, 0, stream>>>(
      z2, cw[0][0], bsum + 0 * 1024, xg, 5120, 1024, 256, 0);

  // state tensor order: 0..5 = enc h1,c1,h2,c2,h3,c3; 6..11 = dec h1,c1,h2,c2,h3,c3
  int pp[12] = {0, 0, 0, 0, 0, 0, 0, 0, 0, 0, 0, 0};
  auto HB = [&](int t, int p) { return states + (size_t)(t * 2 + p) * 65536; };
  const dim3 cgrid(32, 2);

  // ---- encoder recurrence: 20 steps x 3 cells ----
  for (int t = 0; t < 20; ++t) {
    lstm_cell<0><<<cgrid, 256, 0, stream>>>(
        xg + (size_t)t * 256 * 1024, nullptr, nullptr, whhT + 0 * 262144, nullptr,
        HB(0, pp[0]), HB(1, pp[1]), HB(0, pp[0] ^ 1), HB(1, pp[1] ^ 1), nullptr);
    pp[0] ^= 1; pp[1] ^= 1;
    lstm_cell<2><<<cgrid, 256, 0, stream>>>(
        nullptr, HB(0, pp[0]), wihT + 1 * 262144, whhT + 1 * 262144, bsum + 1 * 1024,
        HB(2, pp[2]), HB(3, pp[3]), HB(2, pp[2] ^ 1), HB(3, pp[3] ^ 1), nullptr);
    pp[2] ^= 1; pp[3] ^= 1;
    lstm_cell<2><<<cgrid, 256, 0, stream>>>(
        nullptr, HB(2, pp[2]), wihT + 2 * 262144, whhT + 2 * 262144, bsum + 2 * 1024,
        HB(4, pp[4]), HB(5, pp[5]), HB(4, pp[4] ^ 1), HB(5, pp[5] ^ 1), nullptr);
    pp[4] ^= 1; pp[5] ^= 1;
  }

  // ---- decoder recurrence: 10 steps x 3 cells; h1_dec(0) = enc h3 final ----
  for (int s = 0; s < 10; ++s) {
    const float* h1in = (s == 0) ? HB(4, pp[4]) : HB(6, pp[6]);
    lstm_cell<1><<<cgrid, 256, 0, stream>>>(
        nullptr, nullptr, nullptr, whhT + 3 * 262144, bsum + 3 * 1024,
        h1in, HB(7, pp[7]), HB(6, pp[6] ^ 1), HB(7, pp[7] ^ 1), nullptr);
    pp[6] ^= 1; pp[7] ^= 1;
    lstm_cell<2><<<cgrid, 256, 0, stream>>>(
        nullptr, HB(6, pp[6]), wihT + 4 * 262144, whhT + 4 * 262144, bsum + 4 * 1024,
        HB(8, pp[8]), HB(9, pp[9]), HB(8, pp[8] ^ 1), HB(9, pp[9] ^ 1), nullptr);
    pp[8] ^= 1; pp[9] ^= 1;
    lstm_cell<2><<<cgrid, 256, 0, stream>>>(
        nullptr, HB(8, pp[8]), wihT + 5 * 262144, whhT + 5 * 262144, bsum + 5 * 1024,
        HB(10, pp[10]), HB(11, pp[11]), HB(10, pp[10] ^ 1), HB(11, pp[11] ^ 1),
        H3 + (size_t)s * 65536);
    pp[10] ^= 1; pp[11] ^= 1;
  }

  // ---- batched decoder output FCs over all 10 steps ----
  float* y1 = R1;  // xg dead; reuse
  gemm64<<<dim3(2560 / 64, 1024 / 64), 256, 0, stream>>>(
      H3, w_de1, b_de1, y1, 2560, 1024, 256, 1);
  gemm128<<<dim3(2560 / 128, 4096 / 128), 256, 0, stream>>>(
      y1, w_de2, b_de2, out, 2560, 4096, 1024, 2);

  (void)in_sizes; (void)n_in; (void)out_size; (void)ws_size;
}

// Round 5
// 2341.418 us; speedup vs baseline: 3.3012x; 3.3012x over previous
//
#include <hip/hip_runtime.h>
#include <math.h>

static __device__ __forceinline__ float sigf(float v) { return 1.0f / (1.0f + expf(-v)); }

// ---------------------------------------------------------------------------
// GEMM: C[M,N] = act(A[M,K] @ B[N,K]^T + bias[N]);  act: 0=none, 1=relu, 2=tanh
// 128x64 tile, BK=16, 256 threads, 8x4 per thread.
// Requires M%128==0, N%64==0, K%16==0.
// ---------------------------------------------------------------------------
__global__ __launch_bounds__(256) void gemm128x64(
    const float* __restrict__ A, const float* __restrict__ Bw,
    const float* __restrict__ bias, float* __restrict__ C,
    int M, int N, int K, int act)
{
  __shared__ float As[16][132];
  __shared__ float Bs[16][68];
  const int tid = threadIdx.x;
  const int tm = tid & 15, tn = tid >> 4;
  const int m0 = blockIdx.x * 128, n0 = blockIdx.y * 64;
  float acc[8][4];
#pragma unroll
  for (int i = 0; i < 8; ++i)
#pragma unroll
    for (int j = 0; j < 4; ++j) acc[i][j] = 0.f;

  for (int k0 = 0; k0 < K; k0 += 16) {
    {
      int row = tid >> 1, kc = (tid & 1) * 8;
      float4 a0 = *(const float4*)(A + (size_t)(m0 + row) * K + k0 + kc);
      float4 a1 = *(const float4*)(A + (size_t)(m0 + row) * K + k0 + kc + 4);
      As[kc + 0][row] = a0.x; As[kc + 1][row] = a0.y;
      As[kc + 2][row] = a0.z; As[kc + 3][row] = a0.w;
      As[kc + 4][row] = a1.x; As[kc + 5][row] = a1.y;
      As[kc + 6][row] = a1.z; As[kc + 7][row] = a1.w;
      int brow = tid >> 2, bkc = (tid & 3) * 4;
      float4 b0 = *(const float4*)(Bw + (size_t)(n0 + brow) * K + k0 + bkc);
      Bs[bkc + 0][brow] = b0.x; Bs[bkc + 1][brow] = b0.y;
      Bs[bkc + 2][brow] = b0.z; Bs[bkc + 3][brow] = b0.w;
    }
    __syncthreads();
#pragma unroll
    for (int k = 0; k < 16; ++k) {
      float av[8], bv[4];
      *(float4*)(av)     = *(const float4*)&As[k][tm * 8];
      *(float4*)(av + 4) = *(const float4*)&As[k][tm * 8 + 4];
      *(float4*)(bv)     = *(const float4*)&Bs[k][tn * 4];
#pragma unroll
      for (int i = 0; i < 8; ++i)
#pragma unroll
        for (int j = 0; j < 4; ++j) acc[i][j] = fmaf(av[i], bv[j], acc[i][j]);
    }
    __syncthreads();
  }
#pragma unroll
  for (int i = 0; i < 8; ++i) {
    int row = m0 + tm * 8 + i;
    float o[4];
#pragma unroll
    for (int j = 0; j < 4; ++j) {
      float v = acc[i][j] + bias[n0 + tn * 4 + j];
      if (act == 1) v = fmaxf(v, 0.f);
      else if (act == 2) v = tanhf(v);
      o[j] = v;
    }
    *(float4*)(C + (size_t)row * N + n0 + tn * 4) = *(float4*)o;
  }
}

// ---------------------------------------------------------------------------
// 64x64 tile GEMM (same contract). Requires M%64==0, N%64==0, K%16==0.
// ---------------------------------------------------------------------------
__global__ __launch_bounds__(256) void gemm64(
    const float* __restrict__ A, const float* __restrict__ Bw,
    const float* __restrict__ bias, float* __restrict__ C,
    int M, int N, int K, int act)
{
  __shared__ float As[16][68];
  __shared__ float Bs[16][68];
  const int tid = threadIdx.x;
  const int tm = tid & 15, tn = tid >> 4;
  const int m0 = blockIdx.x * 64, n0 = blockIdx.y * 64;
  float acc[4][4];
#pragma unroll
  for (int i = 0; i < 4; ++i)
#pragma unroll
    for (int j = 0; j < 4; ++j) acc[i][j] = 0.f;

  for (int k0 = 0; k0 < K; k0 += 16) {
    {
      int row = tid >> 2, kc = (tid & 3) << 2;
      float4 a = *(const float4*)(A + (size_t)(m0 + row) * K + k0 + kc);
      As[kc + 0][row] = a.x; As[kc + 1][row] = a.y;
      As[kc + 2][row] = a.z; As[kc + 3][row] = a.w;
      float4 b = *(const float4*)(Bw + (size_t)(n0 + row) * K + k0 + kc);
      Bs[kc + 0][row] = b.x; Bs[kc + 1][row] = b.y;
      Bs[kc + 2][row] = b.z; Bs[kc + 3][row] = b.w;
    }
    __syncthreads();
#pragma unroll
    for (int k = 0; k < 16; ++k) {
      float av[4], bv[4];
      *(float4*)(av) = *(const float4*)&As[k][tm * 4];
      *(float4*)(bv) = *(const float4*)&Bs[k][tn * 4];
#pragma unroll
      for (int i = 0; i < 4; ++i)
#pragma unroll
        for (int j = 0; j < 4; ++j) acc[i][j] = fmaf(av[i], bv[j], acc[i][j]);
    }
    __syncthreads();
  }
#pragma unroll
  for (int i = 0; i < 4; ++i) {
    int row = m0 + tm * 4 + i;
    float o[4];
#pragma unroll
    for (int j = 0; j < 4; ++j) {
      float v = acc[i][j] + bias[n0 + tn * 4 + j];
      if (act == 1) v = fmaxf(v, 0.f);
      else if (act == 2) v = tanhf(v);
      o[j] = v;
    }
    *(float4*)(C + (size_t)row * N + n0 + tn * 4) = *(float4*)o;
  }
}

// ---------------------------------------------------------------------------
// Pack LSTM weights: wP[j][k][s] = w[(s*256+j)*256 + k], s=0..3 (i,f,g,o rows);
// bP[j][s] = bih[s*256+j] + bhh[s*256+j].  grid 256 (j), block 256 (k).
// ---------------------------------------------------------------------------
__global__ __launch_bounds__(256) void prep_pack(
    const float* __restrict__ wih, const float* __restrict__ whh,
    const float* __restrict__ bih, const float* __restrict__ bhh,
    float* __restrict__ wihP, float* __restrict__ whhP, float* __restrict__ bP)
{
  const int j = blockIdx.x, k = threadIdx.x;
  float4 a, c;
  a.x = wih[(0 * 256 + j) * 256 + k];
  a.y = wih[(1 * 256 + j) * 256 + k];
  a.z = wih[(2 * 256 + j) * 256 + k];
  a.w = wih[(3 * 256 + j) * 256 + k];
  *(float4*)&wihP[((size_t)j * 256 + k) * 4] = a;
  c.x = whh[(0 * 256 + j) * 256 + k];
  c.y = whh[(1 * 256 + j) * 256 + k];
  c.z = whh[(2 * 256 + j) * 256 + k];
  c.w = whh[(3 * 256 + j) * 256 + k];
  *(float4*)&whhP[((size_t)j * 256 + k) * 4] = c;
  if (k < 4) bP[j * 4 + k] = bih[k * 256 + j] + bhh[k * 256 + j];
}

// ---------------------------------------------------------------------------
// Per-slab 256x256 transpose: out[t][c][r] = in[t][r][c]. grid (T, 64), 256 thr.
// ---------------------------------------------------------------------------
__global__ __launch_bounds__(256) void transpose256(
    const float* __restrict__ in, float* __restrict__ out)
{
  const int t = blockIdx.x, c4 = blockIdx.y;
  const int r = threadIdx.x;
  float4 v = *(const float4*)(in + ((size_t)t * 256 + r) * 256 + c4 * 4);
  float* op = out + (size_t)t * 65536 + (size_t)(c4 * 4) * 256 + r;
  op[0]   = v.x;
  op[256] = v.y;
  op[512] = v.z;
  op[768] = v.w;
}

// ---------------------------------------------------------------------------
// Weight-stationary LSTM cell. Block j (0..255) owns output unit j's 4 gate
// rows (packed float4 per k). Thread b (0..255) owns batch row b.
// All h/x tensors in TRANSPOSED layout [k][b]. c in [j][b].
// HASX=1: gates = bP + x@wih + h@whh ; HASX=0: x==0 path.
// ---------------------------------------------------------------------------
template <int HASX>
__global__ __launch_bounds__(256) void cell_jb(
    const float* __restrict__ xT,     // [256][256] (k,b), HASX only
    const float* __restrict__ wihP,   // [j][256][4]
    const float* __restrict__ whhP,   // [j][256][4]
    const float* __restrict__ bP,     // [j][4]
    const float* __restrict__ hT_in,  // [256][256]
    const float* __restrict__ c_in,   // [256][256] (j,b)
    float* __restrict__ hT_out,       // [256][256] (j,b)
    float* __restrict__ c_out,        // [256][256] (j,b)
    float* __restrict__ hT_copy)      // optional
{
  const int j = blockIdx.x;
  const int b = threadIdx.x;
  const float4* wh = (const float4*)(whhP + (size_t)j * 1024);
  const float4* wi = (const float4*)(wihP + (size_t)j * 1024);
  float4 acc = ((const float4*)bP)[j];

#pragma unroll 8
  for (int k = 0; k < 256; ++k) {
    const float hv = hT_in[k * 256 + b];
    const float4 w = wh[k];
    acc.x = fmaf(hv, w.x, acc.x);
    acc.y = fmaf(hv, w.y, acc.y);
    acc.z = fmaf(hv, w.z, acc.z);
    acc.w = fmaf(hv, w.w, acc.w);
    if (HASX) {
      const float xv = xT[k * 256 + b];
      const float4 v = wi[k];
      acc.x = fmaf(xv, v.x, acc.x);
      acc.y = fmaf(xv, v.y, acc.y);
      acc.z = fmaf(xv, v.z, acc.z);
      acc.w = fmaf(xv, v.w, acc.w);
    }
  }

  const float cold = c_in[j * 256 + b];
  const float ig = sigf(acc.x), fg = sigf(acc.y);
  const float gg = tanhf(acc.z), og = sigf(acc.w);
  const float cn = fg * cold + ig * gg;
  const float hn = og * tanhf(cn);
  c_out[j * 256 + b] = cn;
  hT_out[j * 256 + b] = hn;
  if (hT_copy) hT_copy[j * 256 + b] = hn;
}

// ---------------------------------------------------------------------------

extern "C" void kernel_launch(void* const* d_in, const int* in_sizes, int n_in,
                              void* d_out, int out_size, void* d_ws, size_t ws_size,
                              hipStream_t stream)
{
  const float* x_in  = (const float*)d_in[0];
  const float* w_en1 = (const float*)d_in[1];
  const float* b_en1 = (const float*)d_in[2];
  const float* w_en2 = (const float*)d_in[3];
  const float* b_en2 = (const float*)d_in[4];
  const float* cw[6][4];
  for (int i = 0; i < 6; ++i)
    for (int j = 0; j < 4; ++j) cw[i][j] = (const float*)d_in[5 + i * 4 + j];
  const float* w_de1 = (const float*)d_in[29];
  const float* b_de1 = (const float*)d_in[30];
  const float* w_de2 = (const float*)d_in[31];
  const float* b_de2 = (const float*)d_in[32];
  float* out = (float*)d_out;

  // ---- workspace layout (floats) ----
  float* ws   = (float*)d_ws;
  float* wihP = ws;                        // 6 * 262144
  float* whhP = wihP + 6 * 262144;         // 6 * 262144
  float* bP   = whhP + 6 * 262144;         // 6 * 1024
  float* st   = bP + 6 * 1024;             // 24 * 65536 states
  float* H3T  = st + 24 * 65536;           // 10 * 65536
  float* R1   = H3T + 10 * 65536;          // 5,242,880: z1 | z2T | (H3std,y1)
  float* R2   = R1 + 5242880;              // 1,310,720: z2

  // ---- weight packing + zero states (every call) ----
  for (int i = 0; i < 6; ++i)
    prep_pack<<<256, 256, 0, stream>>>(cw[i][0], cw[i][1], cw[i][2], cw[i][3],
                                       wihP + i * 262144, whhP + i * 262144,
                                       bP + i * 1024);
  hipMemsetAsync(st, 0, (size_t)24 * 65536 * sizeof(float), stream);

  // ---- batched encoder feedforward ----
  float* z1  = R1;
  float* z2  = R2;
  float* z2T = R1;  // z1 dead after fc_en2
  gemm128x64<<<dim3(5120 / 128, 1024 / 64), 256, 0, stream>>>(
      x_in, w_en1, b_en1, z1, 5120, 1024, 4096, 1);
  gemm64<<<dim3(5120 / 64, 256 / 64), 256, 0, stream>>>(
      z1, w_en2, b_en2, z2, 5120, 256, 1024, 1);
  transpose256<<<dim3(20, 64), 256, 0, stream>>>(z2, z2T);  // [t][b][k]->[t][k][b]

  // state buffers: pairs of [256][256]
  int pp[12] = {0};
  auto SB = [&](int t, int p) { return st + (size_t)(t * 2 + p) * 65536; };
  // 0:hE1 1:cE1 2:hE2 3:cE2 4:hE3 5:cE3 6:hD1 7:cD1 8:hD2 9:cD2 10:hD3 11:cD3

  auto cellX = [&](const float* xT, int wi_, int hI, int cI, float* copy) {
    cell_jb<1><<<256, 256, 0, stream>>>(
        xT, wihP + wi_ * 262144, whhP + wi_ * 262144, bP + wi_ * 1024,
        SB(hI, pp[hI]), SB(cI, pp[cI]),
        SB(hI, pp[hI] ^ 1), SB(cI, pp[cI] ^ 1), copy);
    pp[hI] ^= 1; pp[cI] ^= 1;
  };

  // ---- encoder: 20 steps x 3 cells ----
  for (int t = 0; t < 20; ++t) {
    cellX(z2T + (size_t)t * 65536, 0, 0, 1, nullptr);
    cellX(SB(0, pp[0]),            1, 2, 3, nullptr);
    cellX(SB(2, pp[2]),            2, 4, 5, nullptr);
  }

  // ---- decoder: 10 steps x 3 cells; dec-h1 seeded from enc-h3 final ----
  for (int s = 0; s < 10; ++s) {
    const float* h1in = (s == 0) ? SB(4, pp[4]) : SB(6, pp[6]);
    cell_jb<0><<<256, 256, 0, stream>>>(
        nullptr, nullptr, whhP + 3 * 262144, bP + 3 * 1024,
        h1in, SB(7, pp[7]), SB(6, pp[6] ^ 1), SB(7, pp[7] ^ 1), nullptr);
    pp[6] ^= 1; pp[7] ^= 1;
    cellX(SB(6, pp[6]), 4, 8, 9, nullptr);
    cellX(SB(8, pp[8]), 5, 10, 11, H3T + (size_t)s * 65536);
  }

  // ---- batched decoder output FCs ----
  float* H3std = R1;             // [s*256+b][j]
  float* y1    = R1 + 1310720;   // 2560 x 1024
  transpose256<<<dim3(10, 64), 256, 0, stream>>>(H3T, H3std);  // [s][j][b]->[s][b][j]
  gemm64<<<dim3(2560 / 64, 1024 / 64), 256, 0, stream>>>(
      H3std, w_de1, b_de1, y1, 2560, 1024, 256, 1);
  gemm128x64<<<dim3(2560 / 128, 4096 / 64), 256, 0, stream>>>(
      y1, w_de2, b_de2, out, 2560, 4096, 1024, 2);

  (void)in_sizes; (void)n_in; (void)out_size; (void)ws_size;
}